// Round 15
// baseline (1870.012 us; speedup 1.0000x reference)
//
#include <hip/hip_runtime.h>

// ---------------- problem constants ----------------
#define NUM_ENT   100000
#define NTIMES    10000
#define DD        512
#define DB        768
#define NREL      200
#define NBAS      4
#define NN        30000
#define NEDGE     200000
#define BATCH     128
#define PENT      64
#define PTIME     32
#define TUNIQ     2000
#define V_TOT     110000      // NUM_ENT + NTIMES
#define V_PAD     110208      // 861*128
#define VCONV     6888        // V_PAD/16 conv blocks
#define M_PAD2    30208       // 236*128 (layer GEMM padding)
#define KL        2560        // layer GEMM K
#define KT_L      80          // 2560/32  k-tiles
#define KT_E      16          // 512/32
#define PACKB_BLKS 1280       // 2 sets * 8 colgroups * 320 kchunks / 4 waves
#define GATH_BLKS  7500       // NN/4

typedef __attribute__((ext_vector_type(8))) short s8v;   // 8 x bf16 bits
typedef __attribute__((ext_vector_type(4))) float f4v;   // mfma accumulator

__device__ __forceinline__ unsigned short f2bf(float x){
  unsigned int u = __builtin_bit_cast(unsigned int, x);
  u += 0x7fffu + ((u >> 16) & 1u);
  return (unsigned short)(u >> 16);
}
__device__ __forceinline__ float bf2f(unsigned short h){
  unsigned int u = ((unsigned int)h) << 16;
  return __builtin_bit_cast(float, u);
}

// async global->LDS, 16B per lane; LDS dest is wave-uniform base + lane*16,
// global source is PER-LANE -> stage fragment tiles straight from row-major.
__device__ __forceinline__ void gload16(const void* g, void* l){
  __builtin_amdgcn_global_load_lds(
      (const __attribute__((address_space(1))) void*)g,
      (__attribute__((address_space(3))) void*)l, 16, 0, 0);
}

// LDS fragment tile layout (per 16x32 tile, 1KB): element (lane,j):
//   A: row = rt*16 + (lane&15), k = kt*32 + (lane>>4)*8 + j
//   B: col = ct*16 + (lane&15), k = kt*32 + (lane>>4)*8 + j
// Row-major source chunk for lane: M[row_or_col][k0..k0+7] (16B contiguous).

// ---------------- fused prep: emb->bf16 rowmajor+invnorm | Bt packs | x gather ----
__global__ __launch_bounds__(256) void k_prep(const float* __restrict__ emb,
    const float* __restrict__ basis1, const float* __restrict__ root1,
    const float* __restrict__ basis2, const float* __restrict__ root2,
    const int* __restrict__ x_idx,
    unsigned short* __restrict__ Eb, float* __restrict__ invn,
    unsigned short* __restrict__ Bt1, unsigned short* __restrict__ Bt2,
    unsigned short* __restrict__ Az){
  int bid = blockIdx.x;
  int wid = threadIdx.x >> 6, lane = threadIdx.x & 63;
  if (bid < VCONV){
    // ---- emb f32 -> Eb bf16 row-major + invnorm (pure streaming) ----
    #pragma unroll
    for (int i = 0; i < 4; ++i){
      int row = bid * 16 + wid * 4 + i;
      s8v o;
      float ss = 0.f;
      if (row < V_TOT){
        const float4* p = reinterpret_cast<const float4*>(emb + (size_t)row * DD + lane * 8);
        float4 v0 = p[0], v1 = p[1];
        ss = v0.x*v0.x + v0.y*v0.y + v0.z*v0.z + v0.w*v0.w
           + v1.x*v1.x + v1.y*v1.y + v1.z*v1.z + v1.w*v1.w;
        o[0] = (short)f2bf(v0.x); o[1] = (short)f2bf(v0.y);
        o[2] = (short)f2bf(v0.z); o[3] = (short)f2bf(v0.w);
        o[4] = (short)f2bf(v1.x); o[5] = (short)f2bf(v1.y);
        o[6] = (short)f2bf(v1.z); o[7] = (short)f2bf(v1.w);
      } else {
        #pragma unroll
        for (int j = 0; j < 8; ++j) o[j] = 0;
      }
      *reinterpret_cast<s8v*>(Eb + (size_t)row * 512 + lane * 8) = o;
      ss += __shfl_xor(ss, 1);  ss += __shfl_xor(ss, 2);  ss += __shfl_xor(ss, 4);
      ss += __shfl_xor(ss, 8);  ss += __shfl_xor(ss, 16); ss += __shfl_xor(ss, 32);
      if (lane == 0)
        invn[row] = (row < V_TOT) ? (1.0f / fmaxf(sqrtf(ss), 1e-8f)) : 0.0f;
    }
  } else if (bid < VCONV + PACKB_BLKS){
    // ---- pack basis||root -> Bt row-major [512][2560] (both layers) ----
    int wt = (bid - VCONV) * 4 + wid;          // 0..5119
    int set = wt >= 2560;
    int wt2 = wt - set * 2560;
    int colg = wt2 / 320, kc = wt2 - colg * 320;
    const float* basis = set ? basis2 : basis1;
    const float* root  = set ? root2  : root1;
    unsigned short* Bt = set ? Bt2 : Bt1;
    int col = colg * 64 + lane;
    int k0 = kc * 8;
    s8v o;
    #pragma unroll
    for (int j = 0; j < 8; ++j){
      int k = k0 + j;
      float v = (k < 2048) ? basis[(size_t)k * 512 + col] : root[(size_t)(k - 2048) * 512 + col];
      o[j] = (short)f2bf(v);
    }
    *reinterpret_cast<s8v*>(Bt + (size_t)col * KL + k0) = o;
  } else {
    // ---- gather x rows (f32 emb -> Az x-section, row-major contiguous) ----
    int gb = bid - (VCONV + PACKB_BLKS);
    int w = (int)((gb * 256 + threadIdx.x) >> 6);
    if (w >= NN) return;
    int v = x_idx[w];
    const float4* p = reinterpret_cast<const float4*>(emb + (size_t)v * 512 + lane * 8);
    float4 a = p[0], b = p[1];
    s8v x;
    x[0] = (short)f2bf(a.x); x[1] = (short)f2bf(a.y); x[2] = (short)f2bf(a.z); x[3] = (short)f2bf(a.w);
    x[4] = (short)f2bf(b.x); x[5] = (short)f2bf(b.y); x[6] = (short)f2bf(b.z); x[7] = (short)f2bf(b.w);
    *reinterpret_cast<s8v*>(Az + (size_t)w * KL + 2048 + lane * 8) = x;
  }
}

// ---------------- small dense: q_lin (f32), q_attn (bf16 row-major), p_ent --------
__global__ __launch_bounds__(256) void k_small2(const float* __restrict__ ques,
    const float* __restrict__ Wl, const float* __restrict__ bl,
    const float* __restrict__ Wa, const float* __restrict__ ba,
    const float* __restrict__ Wp, const float* __restrict__ bp,
    float* __restrict__ qlin, unsigned short* __restrict__ qat,
    float* __restrict__ pent){
  if (blockIdx.x == 32){
    int b = threadIdx.x >> 1, half = threadIdx.x & 1;
    float a = 0.f;
    int k0 = half * 384;
    for (int k = k0; k < k0 + 384; ++k)
      a = fmaf(ques[(size_t)b * DB + k], Wp[k], a);
    a += __shfl_xor(a, 1);
    if (half == 0) pent[b] = 1.f / (1.f + expf(-(a + bp[0])));
    return;
  }
  __shared__ float sq[128 * 96];
  int col = threadIdx.x & 31, bg = threadIdx.x >> 5;
  int c0 = blockIdx.x * 32;                  // 0..992 over [Wl|Wa] columns
  const float* W = (c0 < 512) ? Wl : Wa;
  int wcol = (c0 & 511) + col;
  float acc[16] = {};
  for (int k0 = 0; k0 < DB; k0 += 96){
    __syncthreads();
    for (int i = threadIdx.x; i < 128 * 96; i += 256){
      int b = i / 96, kk = i - b * 96;
      sq[i] = ques[(size_t)b * DB + k0 + kk];
    }
    __syncthreads();
    for (int kk = 0; kk < 96; kk += 4){
      float w0 = W[(size_t)(k0 + kk + 0) * 512 + wcol];
      float w1 = W[(size_t)(k0 + kk + 1) * 512 + wcol];
      float w2 = W[(size_t)(k0 + kk + 2) * 512 + wcol];
      float w3 = W[(size_t)(k0 + kk + 3) * 512 + wcol];
      #pragma unroll
      for (int bb = 0; bb < 16; ++bb){
        float4 qv = *reinterpret_cast<const float4*>(&sq[(bg * 16 + bb) * 96 + kk]);
        acc[bb] = fmaf(qv.x, w0, fmaf(qv.y, w1, fmaf(qv.z, w2, fmaf(qv.w, w3, acc[bb]))));
      }
    }
  }
  if (c0 < 512){
    #pragma unroll
    for (int bb = 0; bb < 16; ++bb)
      qlin[(size_t)(bg * 16 + bb) * 512 + wcol] = acc[bb] + bl[wcol];
  } else {
    float bb_ = ba[wcol];
    #pragma unroll
    for (int bb = 0; bb < 16; ++bb)
      qat[(size_t)(bg * 16 + bb) * 512 + wcol] = f2bf(acc[bb] + bb_);
  }
}

// ---------------- 128x128 bf16 MFMA GEMM for M2 (row-major sources) ---------------
// A = qat [128][512]; B = Eb rows NUM_ENT+col; out f32 [128][NTIMES].
__global__ __launch_bounds__(256) void k_gemm_m2(
    const unsigned short* __restrict__ qat, const unsigned short* __restrict__ Eb,
    float* __restrict__ outf){
  __shared__ __align__(1024) short sAll[3 * 8192];
  const int Kt = KT_E;
  int tid = threadIdx.x;
  int lane = tid & 63, wid = tid >> 6;
  int wr = wid >> 1, wc = wid & 1;
  int r16 = lane & 15, kq = lane >> 4;
  int rt0 = blockIdx.x * 8;
  int ct0 = blockIdx.y * 8;
  const unsigned short* pA0 = qat + (size_t)((rt0 + 2 * wid) * 16 + r16) * 512 + kq * 8;
  const unsigned short* pA1 = qat + (size_t)((rt0 + 2 * wid + 1) * 16 + r16) * 512 + kq * 8;
  const unsigned short* pB0 = Eb + (size_t)(NUM_ENT + (ct0 + 2 * wid) * 16 + r16) * 512 + kq * 8;
  const unsigned short* pB1 = Eb + (size_t)(NUM_ENT + (ct0 + 2 * wid + 1) * 16 + r16) * 512 + kq * 8;
  int so = 2 * wid * 512;
  f4v acc[4][4] = {};

  auto STAGE = [&](int buf, int kt){
    short* b = &sAll[buf * 8192];
    gload16(pA0 + kt * 32, b + so);
    gload16(pA1 + kt * 32, b + so + 512);
    gload16(pB0 + kt * 32, b + 4096 + so);
    gload16(pB1 + kt * 32, b + 4096 + so + 512);
  };
  auto COMPUTE = [&](int buf){
    const short* base = &sAll[buf * 8192];
    s8v af[4], bfr[4];
    #pragma unroll
    for (int m = 0; m < 4; ++m) af[m] = *reinterpret_cast<const s8v*>(base + (wr * 4 + m) * 512 + lane * 8);
    #pragma unroll
    for (int n = 0; n < 4; ++n) bfr[n] = *reinterpret_cast<const s8v*>(base + 4096 + (wc * 4 + n) * 512 + lane * 8);
    #pragma unroll
    for (int m = 0; m < 4; ++m)
      #pragma unroll
      for (int n = 0; n < 4; ++n)
        acc[m][n] = __builtin_amdgcn_mfma_f32_16x16x32_bf16(af[m], bfr[n], acc[m][n], 0, 0, 0);
  };

  STAGE(0, 0);
  STAGE(1, 1);
  int cb = 0, sb = 2;
  for (int kt = 0; kt < Kt - 2; ++kt){
    STAGE(sb, kt + 2);
    asm volatile("s_waitcnt vmcnt(8)" ::: "memory");
    __builtin_amdgcn_s_barrier();
    __builtin_amdgcn_sched_barrier(0);
    COMPUTE(cb);
    __builtin_amdgcn_s_barrier();
    cb = (cb == 2) ? 0 : cb + 1;
    sb = (sb == 2) ? 0 : sb + 1;
  }
  asm volatile("s_waitcnt vmcnt(4)" ::: "memory");
  __builtin_amdgcn_s_barrier();
  __builtin_amdgcn_sched_barrier(0);
  COMPUTE(cb);
  cb = (cb == 2) ? 0 : cb + 1;
  asm volatile("s_waitcnt vmcnt(0)" ::: "memory");
  __builtin_amdgcn_s_barrier();
  __builtin_amdgcn_sched_barrier(0);
  COMPUTE(cb);

  #pragma unroll
  for (int m = 0; m < 4; ++m)
    #pragma unroll
    for (int n = 0; n < 4; ++n){
      int row0 = rt0 * 16 + (wr * 4 + m) * 16 + ((lane >> 4) * 4);
      int col  = (ct0 + wc * 4 + n) * 16 + (lane & 15);
      #pragma unroll
      for (int r = 0; r < 4; ++r){
        int rr = row0 + r;
        if (col < NTIMES) outf[(size_t)rr * NTIMES + col] = acc[m][n][r];
      }
    }
}

// ---------------- score GEMM: 30 * pred_n @ emb_n^T (row-major sources) -----------
__global__ __launch_bounds__(256, 3) void k_score_p(
    const unsigned short* __restrict__ predb, const unsigned short* __restrict__ Eb,
    const float* __restrict__ invn, float* __restrict__ out){
  __shared__ __align__(1024) short sAll[3 * 8192];   // 48 KB staging, reused as scratch
  const int Kt = KT_E;
  int tid = threadIdx.x;
  int lane = tid & 63, wid = tid >> 6;
  int wr = wid >> 1, wc = wid & 1;
  int kq = lane >> 4, r16 = lane & 15;
  int ct0 = blockIdx.x * 8;
  const unsigned short* pA0 = predb + (size_t)(2 * wid * 16 + r16) * 512 + kq * 8;
  const unsigned short* pA1 = predb + (size_t)((2 * wid + 1) * 16 + r16) * 512 + kq * 8;
  const unsigned short* pB0 = Eb + (size_t)((ct0 + 2 * wid) * 16 + r16) * 512 + kq * 8;
  const unsigned short* pB1 = Eb + (size_t)((ct0 + 2 * wid + 1) * 16 + r16) * 512 + kq * 8;
  int so = 2 * wid * 512;
  f4v acc[4][4] = {};

  auto STAGE = [&](int buf, int kt){
    short* b = &sAll[buf * 8192];
    gload16(pA0 + kt * 32, b + so);
    gload16(pA1 + kt * 32, b + so + 512);
    gload16(pB0 + kt * 32, b + 4096 + so);
    gload16(pB1 + kt * 32, b + 4096 + so + 512);
  };
  auto COMPUTE = [&](int buf){
    const short* base = &sAll[buf * 8192];
    s8v af[4], bfr[4];
    #pragma unroll
    for (int m = 0; m < 4; ++m) af[m] = *reinterpret_cast<const s8v*>(base + (wr * 4 + m) * 512 + lane * 8);
    #pragma unroll
    for (int n = 0; n < 4; ++n) bfr[n] = *reinterpret_cast<const s8v*>(base + 4096 + (wc * 4 + n) * 512 + lane * 8);
    #pragma unroll
    for (int m = 0; m < 4; ++m)
      #pragma unroll
      for (int n = 0; n < 4; ++n)
        acc[m][n] = __builtin_amdgcn_mfma_f32_16x16x32_bf16(af[m], bfr[n], acc[m][n], 0, 0, 0);
  };

  STAGE(0, 0);
  STAGE(1, 1);
  int cb = 0, sb = 2;
  for (int kt = 0; kt < Kt - 2; ++kt){
    STAGE(sb, kt + 2);
    asm volatile("s_waitcnt vmcnt(8)" ::: "memory");
    __builtin_amdgcn_s_barrier();
    __builtin_amdgcn_sched_barrier(0);
    COMPUTE(cb);
    __builtin_amdgcn_s_barrier();
    cb = (cb == 2) ? 0 : cb + 1;
    sb = (sb == 2) ? 0 : sb + 1;
  }
  asm volatile("s_waitcnt vmcnt(4)" ::: "memory");
  __builtin_amdgcn_s_barrier();
  __builtin_amdgcn_sched_barrier(0);
  COMPUTE(cb);
  cb = (cb == 2) ? 0 : cb + 1;
  asm volatile("s_waitcnt vmcnt(0)" ::: "memory");
  __builtin_amdgcn_s_barrier();
  __builtin_amdgcn_sched_barrier(0);
  COMPUTE(cb);

  // ---- epilogue: per-wave LDS transpose -> coalesced float4 row stores ----
  __syncthreads();                                   // staging LDS now reusable
  float* scratch = reinterpret_cast<float*>(sAll) + wid * 2176;   // 32 rows x 68
  int colg = ct0 * 16 + wc * 64 + r16 * 4;           // this lane's 4-col base
  bool c_ok = colg < V_TOT;                          // V_TOT % 4 == 0
  float4 inv4 = float4{0.f, 0.f, 0.f, 0.f};
  if (c_ok){
    inv4 = *reinterpret_cast<const float4*>(invn + colg);
    inv4.x *= 30.f; inv4.y *= 30.f; inv4.z *= 30.f; inv4.w *= 30.f;
  }
  #pragma unroll
  for (int p = 0; p < 2; ++p){
    #pragma unroll
    for (int mm = 0; mm < 2; ++mm){
      int m = p * 2 + mm;
      #pragma unroll
      for (int n = 0; n < 4; ++n)
        #pragma unroll
        for (int r = 0; r < 4; ++r)
          scratch[(mm * 16 + kq * 4 + r) * 68 + n * 16 + r16] = acc[m][n][r];
    }
    #pragma unroll
    for (int i = 0; i < 8; ++i){
      int row_r = i * 4 + kq;                        // 0..31
      float4 v = *reinterpret_cast<const float4*>(scratch + row_r * 68 + r16 * 4);
      if (c_ok){
        float4 o;
        o.x = v.x * inv4.x; o.y = v.y * inv4.y; o.z = v.z * inv4.z; o.w = v.w * inv4.w;
        int grr = wr * 64 + p * 32 + row_r;
        *reinterpret_cast<float4*>(out + (size_t)grr * V_TOT + colg) = o;
      }
    }
  }
}

// ---------------- 128x512 bf16 MFMA GEMM, row-major A [M][2560], Bt [512][2560] ----
// Depth-2 ring, 80 KB LDS -> 2 blocks/CU (TLP hides per-step latency).
// MODE 1: h1 -> Az h-section (in-place, per-block rows only). MODE 2: h2 row-major.
template<int MODE>
__global__ __launch_bounds__(512, 4) void k_gemm512(
    const unsigned short* __restrict__ A, const unsigned short* __restrict__ Bt,
    const float* __restrict__ bias, unsigned short* __restrict__ outh,
    unsigned short* __restrict__ Az_h){
  __shared__ __align__(1024) short sAll[2 * 20480];  // 2 bufs x (A 8KB + B 32KB) = 80KB
  const int Kt = KT_L;
  int tid = threadIdx.x;
  int lane = tid & 63, wid = tid >> 6;               // 8 waves
  int wr = wid >> 2, wc = wid & 3;                   // 2x4 wave grid, wave-tile 64x128
  int r16 = lane & 15, kq = lane >> 4;
  int blk = blockIdx.x;                              // 236 blocks
  // A: wave stages rows blk*128 + wid*16 + r16, 16B chunk at k = kt*32 + kq*8
  const unsigned short* pA = A + (size_t)(blk * 128 + wid * 16 + r16) * KL + kq * 8;
  // B: wave stages col-tiles wid*4+c -> Bt rows (wid*4+c)*16 + r16
  const unsigned short* pB0 = Bt + (size_t)((wid * 4 + 0) * 16 + r16) * KL + kq * 8;
  const unsigned short* pB1 = Bt + (size_t)((wid * 4 + 1) * 16 + r16) * KL + kq * 8;
  const unsigned short* pB2 = Bt + (size_t)((wid * 4 + 2) * 16 + r16) * KL + kq * 8;
  const unsigned short* pB3 = Bt + (size_t)((wid * 4 + 3) * 16 + r16) * KL + kq * 8;
  int soA = wid * 512;
  int soB = 4096 + wid * 4 * 512;
  f4v acc[4][8] = {};

  auto STAGE = [&](int buf, int kt){
    short* b = &sAll[buf * 20480];
    gload16(pA  + kt * 32, b + soA);
    gload16(pB0 + kt * 32, b + soB);
    gload16(pB1 + kt * 32, b + soB +  512);
    gload16(pB2 + kt * 32, b + soB + 1024);
    gload16(pB3 + kt * 32, b + soB + 1536);
  };
  auto COMPUTE = [&](int buf){
    const short* base = &sAll[buf * 20480];
    s8v af[4], bfr[8];
    #pragma unroll
    for (int m = 0; m < 4; ++m) af[m] = *reinterpret_cast<const s8v*>(base + (wr * 4 + m) * 512 + lane * 8);
    #pragma unroll
    for (int n = 0; n < 8; ++n) bfr[n] = *reinterpret_cast<const s8v*>(base + 4096 + (wc * 8 + n) * 512 + lane * 8);
    __builtin_amdgcn_s_setprio(1);
    #pragma unroll
    for (int m = 0; m < 4; ++m)
      #pragma unroll
      for (int n = 0; n < 8; ++n)
        acc[m][n] = __builtin_amdgcn_mfma_f32_16x16x32_bf16(af[m], bfr[n], acc[m][n], 0, 0, 0);
    __builtin_amdgcn_s_setprio(0);
  };

  STAGE(0, 0);
  int cb = 0;
  for (int kt = 0; kt < Kt - 1; ++kt){
    STAGE(cb ^ 1, kt + 1);                 // 5 next-step loads issued
    asm volatile("s_waitcnt vmcnt(5)" ::: "memory");   // current step's 5 landed
    __builtin_amdgcn_s_barrier();
    __builtin_amdgcn_sched_barrier(0);
    COMPUTE(cb);
    __builtin_amdgcn_s_barrier();          // reads done before next STAGE overwrites
    cb ^= 1;
  }
  asm volatile("s_waitcnt vmcnt(0)" ::: "memory");
  __builtin_amdgcn_s_barrier();
  __builtin_amdgcn_sched_barrier(0);
  COMPUTE(cb);

  int R0 = blk * 128 + wr * 64 + ((lane >> 4) * 4);
  int C0 = wc * 128 + (lane & 15);
  #pragma unroll
  for (int m = 0; m < 4; ++m)
    #pragma unroll
    for (int r4 = 0; r4 < 4; ++r4){
      int rr = R0 + m * 16 + r4;
      if (rr < NN){
        #pragma unroll
        for (int n = 0; n < 8; ++n){
          int col = C0 + n * 16;
          float v = acc[m][n][r4] + bias[col];
          if constexpr (MODE == 1){
            v = fmaxf(v, 0.f);
            Az_h[(size_t)rr * KL + 2048 + col] = f2bf(v);   // in-place h-section
          } else {
            outh[(size_t)rr * 512 + col] = f2bf(v);
          }
        }
      }
    }
}

// ---------------- fused per-edge gate weight + dst bucketing ----------------
__global__ __launch_bounds__(256) void k_edgeprep(const int* __restrict__ ebatch,
    const int* __restrict__ st, const int* __restrict__ et,
    const float* __restrict__ enorm, const float* __restrict__ M2,
    const int* __restrict__ ei,
    float* __restrict__ we, int* __restrict__ cnt, int* __restrict__ lists){
  int e = blockIdx.x * 256 + threadIdx.x;
  if (e >= NEDGE) return;
  int b = ebatch[e];
  float s = 0.5f * (M2[(size_t)b * NTIMES + st[e]] + M2[(size_t)b * NTIMES + et[e]]);
  we[e] = (1.f / (1.f + expf(-s))) * enorm[e];
  int dst = ei[NEDGE + e];
  int slot = atomicAdd(&cnt[dst], 1);
  if (slot < 64) lists[(size_t)dst * 64 + slot] = e;
}

// ---------------- edge aggregation: z[n,b,:] += (w*att[t,b]) * x[src,:] -----------
// xsrc: row-major with row stride KL (Az h/x-section); z written row-major to Az.
__global__ __launch_bounds__(256) void k_edge_agg(const unsigned short* __restrict__ xsrc,
    const int* __restrict__ ei, const int* __restrict__ etype,
    const float* __restrict__ we, const float* __restrict__ att,
    const int* __restrict__ cnt, const int* __restrict__ lists,
    unsigned short* __restrict__ Az){
  __shared__ float satt[NREL * NBAS];
  __shared__ int sed[4][64];
  for (int i = threadIdx.x; i < NREL * NBAS; i += 256) satt[i] = att[i];
  int wid = threadIdx.x >> 6, lane = threadIdx.x & 63;
  int n = blockIdx.x * 4 + wid;
  int deg = min(cnt[n], 64);
  int eid = (lane < deg) ? lists[(size_t)n * 64 + lane] : 0x7fffffff;
  int rank = 0;
  for (int j = 0; j < 64; ++j){
    int v = __shfl(eid, j);
    rank += (v < eid) ? 1 : 0;
  }
  __syncthreads();
  if (lane < deg) sed[wid][rank] = eid;
  __syncthreads();
  float acc[NBAS][8] = {};
  if (deg > 0){
    int my_e = sed[wid][(lane < deg) ? lane : 0];
    int my_s = ei[my_e];
    int my_t = etype[my_e];
    float my_w = we[my_e];
    float c0l = my_w * satt[my_t * 4 + 0];
    float c1l = my_w * satt[my_t * 4 + 1];
    float c2l = my_w * satt[my_t * 4 + 2];
    float c3l = my_w * satt[my_t * 4 + 3];
    int s0 = __shfl(my_s, 0);
    s8v xv = *reinterpret_cast<const s8v*>(xsrc + (size_t)s0 * KL + lane * 8);
    for (int j = 0; j < deg; ++j){
      s8v xn = xv;
      if (j + 1 < deg){
        int sn = __shfl(my_s, j + 1);
        xn = *reinterpret_cast<const s8v*>(xsrc + (size_t)sn * KL + lane * 8);
      }
      float c0 = __shfl(c0l, j), c1 = __shfl(c1l, j);
      float c2 = __shfl(c2l, j), c3 = __shfl(c3l, j);
      #pragma unroll
      for (int jj = 0; jj < 8; ++jj){
        float x = bf2f((unsigned short)xv[jj]);
        acc[0][jj] = fmaf(c0, x, acc[0][jj]);
        acc[1][jj] = fmaf(c1, x, acc[1][jj]);
        acc[2][jj] = fmaf(c2, x, acc[2][jj]);
        acc[3][jj] = fmaf(c3, x, acc[3][jj]);
      }
      xv = xn;
    }
  }
  #pragma unroll
  for (int b = 0; b < NBAS; ++b){
    s8v o;
    #pragma unroll
    for (int jj = 0; jj < 8; ++jj) o[jj] = (short)f2bf(acc[b][jj]);
    *reinterpret_cast<s8v*>(Az + (size_t)n * KL + b * 512 + lane * 8) = o;
  }
}

// ---------------- pooling + pred assembly + normalize (row-major bf16 out) --------
__global__ __launch_bounds__(256) void k_pred(const unsigned short* __restrict__ h2,
    const float* __restrict__ emb, const int* __restrict__ uniq,
    const int* __restrict__ pent_idx, const int* __restrict__ ptime_idx,
    const int* __restrict__ ent_c, const int* __restrict__ time_c,
    const float* __restrict__ qlin, const float* __restrict__ pent,
    unsigned short* __restrict__ predb){
  __shared__ float sacc[4][512];
  int b = blockIdx.x;
  int wid = threadIdx.x >> 6, lane = threadIdx.x & 63;
  float a[8] = {};
  if (wid < 2){
    for (int j = wid * 32; j < wid * 32 + 32; ++j){
      int idx = pent_idx[b * PENT + j];
      if (idx < NN){
        s8v hv = *reinterpret_cast<const s8v*>(h2 + (size_t)idx * 512 + lane * 8);
        #pragma unroll
        for (int jj = 0; jj < 8; ++jj) a[jj] += bf2f((unsigned short)hv[jj]);
      }
    }
  } else {
    for (int j = (wid - 2) * 16; j < (wid - 2) * 16 + 16; ++j){
      int ti = ptime_idx[b * PTIME + j];
      if (ti < TUNIQ){
        const float* p = emb + (size_t)(NUM_ENT + uniq[ti]) * 512 + lane * 8;
        #pragma unroll
        for (int jj = 0; jj < 8; ++jj) a[jj] += p[jj];
      }
    }
  }
  #pragma unroll
  for (int jj = 0; jj < 8; ++jj) sacc[wid][lane * 8 + jj] = a[jj];
  __syncthreads();
  if (wid == 0){
    float ce = 1.f / (float)ent_c[b], ct = 1.f / (float)time_c[b];
    float p = pent[b];
    float pr[8]; float ss = 0.f;
    #pragma unroll
    for (int jj = 0; jj < 8; ++jj){
      int i = lane * 8 + jj;
      float ae = sacc[0][i] + sacc[1][i];
      float at = sacc[2][i] + sacc[3][i];
      float v = (qlin[(size_t)b * 512 + i] + ae * ce * p + at * ct * (1.f - p)) * (1.f / 3.f);
      pr[jj] = v; ss += v * v;
    }
    ss += __shfl_xor(ss, 32); ss += __shfl_xor(ss, 16); ss += __shfl_xor(ss, 8);
    ss += __shfl_xor(ss, 4);  ss += __shfl_xor(ss, 2);  ss += __shfl_xor(ss, 1);
    float inv = 1.f / fmaxf(sqrtf(ss), 1e-8f);
    s8v o;
    #pragma unroll
    for (int jj = 0; jj < 8; ++jj) o[jj] = (short)f2bf(pr[jj] * inv);
    *reinterpret_cast<s8v*>(predb + (size_t)b * 512 + lane * 8) = o;
  }
}

// ---------------- launch ----------------
extern "C" void kernel_launch(void* const* d_in, const int* in_sizes, int n_in,
                              void* d_out, int out_size, void* d_ws, size_t ws_size,
                              hipStream_t stream){
  const float* emb    = (const float*)d_in[0];
  const float* basis1 = (const float*)d_in[1];
  const float* att1   = (const float*)d_in[2];
  const float* root1  = (const float*)d_in[3];
  const float* bias1  = (const float*)d_in[4];
  const float* basis2 = (const float*)d_in[5];
  const float* att2   = (const float*)d_in[6];
  const float* root2  = (const float*)d_in[7];
  const float* bias2  = (const float*)d_in[8];
  const float* W_lin  = (const float*)d_in[9];
  const float* b_lin  = (const float*)d_in[10];
  const float* W_attn = (const float*)d_in[11];
  const float* b_attn = (const float*)d_in[12];
  const float* W_prob = (const float*)d_in[13];
  const float* b_prob = (const float*)d_in[14];
  const float* ques   = (const float*)d_in[15];
  const int* x_idx    = (const int*)d_in[16];
  const int* eidx     = (const int*)d_in[17];
  const int* etype    = (const int*)d_in[18];
  const int* stime    = (const int*)d_in[19];
  const int* etime    = (const int*)d_in[20];
  const int* ebatch   = (const int*)d_in[21];
  const float* enorm  = (const float*)d_in[22];
  const int* uniq     = (const int*)d_in[23];
  const int* pent_i   = (const int*)d_in[24];
  const int* ptime_i  = (const int*)d_in[25];
  const int* ent_c    = (const int*)d_in[26];
  const int* time_c   = (const int*)d_in[27];
  float* out = (float*)d_out;

  char* w = (char*)d_ws;
  size_t off = 0;
  auto alloc = [&](size_t bytes)->char*{ char* p = w + off; off += (bytes + 255) & ~(size_t)255; return p; };
  unsigned short* Eb   = (unsigned short*)alloc((size_t)V_PAD * 512 * 2);        // 112.9 MB
  float*          invn = (float*)alloc((size_t)V_PAD * 4);
  unsigned short* Az   = (unsigned short*)alloc((size_t)M_PAD2 * KL * 2);        // 154.7 MB
  unsigned short* Bt1  = (unsigned short*)alloc((size_t)512 * KL * 2);
  unsigned short* Bt2  = (unsigned short*)alloc((size_t)512 * KL * 2);
  unsigned short* h2   = (unsigned short*)alloc((size_t)NN * 512 * 2);           // 30.7 MB
  float* M2    = (float*)alloc((size_t)BATCH * NTIMES * 4);
  float* we    = (float*)alloc((size_t)NEDGE * 4);
  float* qlin  = (float*)alloc((size_t)BATCH * 512 * 4);
  float* pent  = (float*)alloc(1024);
  unsigned short* qat   = (unsigned short*)alloc((size_t)BATCH * 512 * 2);
  unsigned short* predb = (unsigned short*)alloc((size_t)BATCH * 512 * 2);
  int* cnt   = (int*)alloc((size_t)NN * 4);
  int* lists = (int*)alloc((size_t)NN * 64 * 4);
  (void)ws_size; (void)in_sizes; (void)n_in; (void)out_size;

  // 1. fused prep: Eb+invnorms | Bt packs | x gather into Az x-section
  k_prep<<<VCONV + PACKB_BLKS + GATH_BLKS, 256, 0, stream>>>(
      emb, basis1, root1, basis2, root2, x_idx,
      Eb, invn, Bt1, Bt2, Az);
  // 2. question projections
  k_small2<<<33, 256, 0, stream>>>(ques, W_lin, b_lin, W_attn, b_attn, W_prob, b_prob,
                                   qlin, qat, pent);
  // 3. M2 = q_attn @ time_emb^T
  k_gemm_m2<<<dim3(1, 79), 256, 0, stream>>>(qat, Eb, M2);
  // 4. fused edge gate + bucketing
  hipMemsetAsync(cnt, 0, (size_t)NN * 4, stream);
  k_edgeprep<<<(NEDGE + 255) / 256, 256, 0, stream>>>(ebatch, stime, etime, enorm, M2,
                                                      eidx, we, cnt, lists);
  // 5. layer 1: agg (x from Az x-section) -> gemm (h1 written in-place to x-section)
  k_edge_agg<<<NN / 4, 256, 0, stream>>>(Az + 2048, eidx, etype, we, att1, cnt, lists, Az);
  k_gemm512<1><<<236, 512, 0, stream>>>(Az, Bt1, bias1, nullptr, Az);
  // 6. layer 2: agg (h1 from same slot) -> gemm (h2 row-major)
  k_edge_agg<<<NN / 4, 256, 0, stream>>>(Az + 2048, eidx, etype, we, att2, cnt, lists, Az);
  k_gemm512<2><<<236, 512, 0, stream>>>(Az, Bt2, bias2, h2, nullptr);
  // 7. pooling + pred (row-major bf16)
  k_pred<<<BATCH, 256, 0, stream>>>(h2, emb, uniq, pent_i, ptime_i, ent_c, time_c,
                                    qlin, pent, predb);
  // 8. score = 30 * pred_n @ emb_n^T
  k_score_p<<<861, 256, 0, stream>>>(predb, Eb, invn, out);
}

// Round 16
// 664.595 us; speedup vs baseline: 2.8138x; 2.8138x over previous
//
#include <hip/hip_runtime.h>

// ---------------- problem constants ----------------
#define NUM_ENT   100000
#define NTIMES    10000
#define DD        512
#define DB        768
#define NREL      200
#define NBAS      4
#define NN        30000
#define NEDGE     200000
#define BATCH     128
#define PENT      64
#define PTIME     32
#define TUNIQ     2000
#define V_TOT     110000      // NUM_ENT + NTIMES
#define V_PAD     110208      // 861*128
#define VCONV     6888        // V_PAD/16 conv blocks
#define M_PAD2    30208       // 236*128 (layer GEMM padding)
#define KL        2560        // layer GEMM K
#define KT_L      80          // 2560/32  k-tiles
#define KT_E      16          // 512/32
#define PACKB_BLKS 1280       // 2 sets * 8 colgroups * 320 kchunks / 4 waves
#define GATH_BLKS  7500       // NN/4

typedef __attribute__((ext_vector_type(8))) short s8v;   // 8 x bf16 bits
typedef __attribute__((ext_vector_type(4))) float f4v;   // mfma accumulator

__device__ __forceinline__ unsigned short f2bf(float x){
  unsigned int u = __builtin_bit_cast(unsigned int, x);
  u += 0x7fffu + ((u >> 16) & 1u);
  return (unsigned short)(u >> 16);
}
__device__ __forceinline__ float bf2f(unsigned short h){
  unsigned int u = ((unsigned int)h) << 16;
  return __builtin_bit_cast(float, u);
}

// async global->LDS, 16B per lane; LDS dest is wave-uniform base + lane*16,
// global source is PER-LANE -> stage fragment tiles straight from row-major.
__device__ __forceinline__ void gload16(const void* g, void* l){
  __builtin_amdgcn_global_load_lds(
      (const __attribute__((address_space(1))) void*)g,
      (__attribute__((address_space(3))) void*)l, 16, 0, 0);
}

// LDS fragment tile layout (per 16x32 tile, 1KB): element (lane,j):
//   A: row = rt*16 + (lane&15), k = kt*32 + (lane>>4)*8 + j
//   B: col = ct*16 + (lane&15), k = kt*32 + (lane>>4)*8 + j
// Row-major source chunk for lane: M[row_or_col][k0..k0+7] (16B contiguous).

// ---------------- fused prep: emb->bf16 rowmajor+invnorm | Bt packs | x gather ----
__global__ __launch_bounds__(256) void k_prep(const float* __restrict__ emb,
    const float* __restrict__ basis1, const float* __restrict__ root1,
    const float* __restrict__ basis2, const float* __restrict__ root2,
    const int* __restrict__ x_idx,
    unsigned short* __restrict__ Eb, float* __restrict__ invn,
    unsigned short* __restrict__ Bt1, unsigned short* __restrict__ Bt2,
    unsigned short* __restrict__ Az){
  int bid = blockIdx.x;
  int wid = threadIdx.x >> 6, lane = threadIdx.x & 63;
  if (bid < VCONV){
    // ---- emb f32 -> Eb bf16 row-major + invnorm (pure streaming) ----
    #pragma unroll
    for (int i = 0; i < 4; ++i){
      int row = bid * 16 + wid * 4 + i;
      s8v o;
      float ss = 0.f;
      if (row < V_TOT){
        const float4* p = reinterpret_cast<const float4*>(emb + (size_t)row * DD + lane * 8);
        float4 v0 = p[0], v1 = p[1];
        ss = v0.x*v0.x + v0.y*v0.y + v0.z*v0.z + v0.w*v0.w
           + v1.x*v1.x + v1.y*v1.y + v1.z*v1.z + v1.w*v1.w;
        o[0] = (short)f2bf(v0.x); o[1] = (short)f2bf(v0.y);
        o[2] = (short)f2bf(v0.z); o[3] = (short)f2bf(v0.w);
        o[4] = (short)f2bf(v1.x); o[5] = (short)f2bf(v1.y);
        o[6] = (short)f2bf(v1.z); o[7] = (short)f2bf(v1.w);
      } else {
        #pragma unroll
        for (int j = 0; j < 8; ++j) o[j] = 0;
      }
      *reinterpret_cast<s8v*>(Eb + (size_t)row * 512 + lane * 8) = o;
      ss += __shfl_xor(ss, 1);  ss += __shfl_xor(ss, 2);  ss += __shfl_xor(ss, 4);
      ss += __shfl_xor(ss, 8);  ss += __shfl_xor(ss, 16); ss += __shfl_xor(ss, 32);
      if (lane == 0)
        invn[row] = (row < V_TOT) ? (1.0f / fmaxf(sqrtf(ss), 1e-8f)) : 0.0f;
    }
  } else if (bid < VCONV + PACKB_BLKS){
    // ---- pack basis||root -> Bt row-major [512][2560] (both layers) ----
    int wt = (bid - VCONV) * 4 + wid;          // 0..5119
    int set = wt >= 2560;
    int wt2 = wt - set * 2560;
    int colg = wt2 / 320, kc = wt2 - colg * 320;
    const float* basis = set ? basis2 : basis1;
    const float* root  = set ? root2  : root1;
    unsigned short* Bt = set ? Bt2 : Bt1;
    int col = colg * 64 + lane;
    int k0 = kc * 8;
    s8v o;
    #pragma unroll
    for (int j = 0; j < 8; ++j){
      int k = k0 + j;
      float v = (k < 2048) ? basis[(size_t)k * 512 + col] : root[(size_t)(k - 2048) * 512 + col];
      o[j] = (short)f2bf(v);
    }
    *reinterpret_cast<s8v*>(Bt + (size_t)col * KL + k0) = o;
  } else {
    // ---- gather x rows (f32 emb -> Az x-section, row-major contiguous) ----
    int gb = bid - (VCONV + PACKB_BLKS);
    int w = (int)((gb * 256 + threadIdx.x) >> 6);
    if (w >= NN) return;
    int v = x_idx[w];
    const float4* p = reinterpret_cast<const float4*>(emb + (size_t)v * 512 + lane * 8);
    float4 a = p[0], b = p[1];
    s8v x;
    x[0] = (short)f2bf(a.x); x[1] = (short)f2bf(a.y); x[2] = (short)f2bf(a.z); x[3] = (short)f2bf(a.w);
    x[4] = (short)f2bf(b.x); x[5] = (short)f2bf(b.y); x[6] = (short)f2bf(b.z); x[7] = (short)f2bf(b.w);
    *reinterpret_cast<s8v*>(Az + (size_t)w * KL + 2048 + lane * 8) = x;
  }
}

// ---------------- small dense: q_lin (f32), q_attn (bf16 row-major), p_ent --------
__global__ __launch_bounds__(256) void k_small2(const float* __restrict__ ques,
    const float* __restrict__ Wl, const float* __restrict__ bl,
    const float* __restrict__ Wa, const float* __restrict__ ba,
    const float* __restrict__ Wp, const float* __restrict__ bp,
    float* __restrict__ qlin, unsigned short* __restrict__ qat,
    float* __restrict__ pent){
  if (blockIdx.x == 32){
    int b = threadIdx.x >> 1, half = threadIdx.x & 1;
    float a = 0.f;
    int k0 = half * 384;
    for (int k = k0; k < k0 + 384; ++k)
      a = fmaf(ques[(size_t)b * DB + k], Wp[k], a);
    a += __shfl_xor(a, 1);
    if (half == 0) pent[b] = 1.f / (1.f + expf(-(a + bp[0])));
    return;
  }
  __shared__ float sq[128 * 96];
  int col = threadIdx.x & 31, bg = threadIdx.x >> 5;
  int c0 = blockIdx.x * 32;                  // 0..992 over [Wl|Wa] columns
  const float* W = (c0 < 512) ? Wl : Wa;
  int wcol = (c0 & 511) + col;
  float acc[16] = {};
  for (int k0 = 0; k0 < DB; k0 += 96){
    __syncthreads();
    for (int i = threadIdx.x; i < 128 * 96; i += 256){
      int b = i / 96, kk = i - b * 96;
      sq[i] = ques[(size_t)b * DB + k0 + kk];
    }
    __syncthreads();
    for (int kk = 0; kk < 96; kk += 4){
      float w0 = W[(size_t)(k0 + kk + 0) * 512 + wcol];
      float w1 = W[(size_t)(k0 + kk + 1) * 512 + wcol];
      float w2 = W[(size_t)(k0 + kk + 2) * 512 + wcol];
      float w3 = W[(size_t)(k0 + kk + 3) * 512 + wcol];
      #pragma unroll
      for (int bb = 0; bb < 16; ++bb){
        float4 qv = *reinterpret_cast<const float4*>(&sq[(bg * 16 + bb) * 96 + kk]);
        acc[bb] = fmaf(qv.x, w0, fmaf(qv.y, w1, fmaf(qv.z, w2, fmaf(qv.w, w3, acc[bb]))));
      }
    }
  }
  if (c0 < 512){
    #pragma unroll
    for (int bb = 0; bb < 16; ++bb)
      qlin[(size_t)(bg * 16 + bb) * 512 + wcol] = acc[bb] + bl[wcol];
  } else {
    float bb_ = ba[wcol];
    #pragma unroll
    for (int bb = 0; bb < 16; ++bb)
      qat[(size_t)(bg * 16 + bb) * 512 + wcol] = f2bf(acc[bb] + bb_);
  }
}

// ---------------- 128x128 bf16 MFMA GEMM for M2 (row-major sources) ---------------
// A = qat [128][512]; B = Eb rows NUM_ENT+col; out f32 [128][NTIMES].
__global__ __launch_bounds__(256) void k_gemm_m2(
    const unsigned short* __restrict__ qat, const unsigned short* __restrict__ Eb,
    float* __restrict__ outf){
  __shared__ __align__(1024) short sAll[3 * 8192];
  const int Kt = KT_E;
  int tid = threadIdx.x;
  int lane = tid & 63, wid = tid >> 6;
  int wr = wid >> 1, wc = wid & 1;
  int r16 = lane & 15, kq = lane >> 4;
  int rt0 = blockIdx.x * 8;
  int ct0 = blockIdx.y * 8;
  const unsigned short* pA0 = qat + (size_t)((rt0 + 2 * wid) * 16 + r16) * 512 + kq * 8;
  const unsigned short* pA1 = qat + (size_t)((rt0 + 2 * wid + 1) * 16 + r16) * 512 + kq * 8;
  const unsigned short* pB0 = Eb + (size_t)(NUM_ENT + (ct0 + 2 * wid) * 16 + r16) * 512 + kq * 8;
  const unsigned short* pB1 = Eb + (size_t)(NUM_ENT + (ct0 + 2 * wid + 1) * 16 + r16) * 512 + kq * 8;
  int so = 2 * wid * 512;
  f4v acc[4][4] = {};

  auto STAGE = [&](int buf, int kt){
    short* b = &sAll[buf * 8192];
    gload16(pA0 + kt * 32, b + so);
    gload16(pA1 + kt * 32, b + so + 512);
    gload16(pB0 + kt * 32, b + 4096 + so);
    gload16(pB1 + kt * 32, b + 4096 + so + 512);
  };
  auto COMPUTE = [&](int buf){
    const short* base = &sAll[buf * 8192];
    s8v af[4], bfr[4];
    #pragma unroll
    for (int m = 0; m < 4; ++m) af[m] = *reinterpret_cast<const s8v*>(base + (wr * 4 + m) * 512 + lane * 8);
    #pragma unroll
    for (int n = 0; n < 4; ++n) bfr[n] = *reinterpret_cast<const s8v*>(base + 4096 + (wc * 4 + n) * 512 + lane * 8);
    #pragma unroll
    for (int m = 0; m < 4; ++m)
      #pragma unroll
      for (int n = 0; n < 4; ++n)
        acc[m][n] = __builtin_amdgcn_mfma_f32_16x16x32_bf16(af[m], bfr[n], acc[m][n], 0, 0, 0);
  };

  STAGE(0, 0);
  STAGE(1, 1);
  int cb = 0, sb = 2;
  for (int kt = 0; kt < Kt - 2; ++kt){
    STAGE(sb, kt + 2);
    asm volatile("s_waitcnt vmcnt(8)" ::: "memory");
    __builtin_amdgcn_s_barrier();
    __builtin_amdgcn_sched_barrier(0);
    COMPUTE(cb);
    __builtin_amdgcn_s_barrier();
    cb = (cb == 2) ? 0 : cb + 1;
    sb = (sb == 2) ? 0 : sb + 1;
  }
  asm volatile("s_waitcnt vmcnt(4)" ::: "memory");
  __builtin_amdgcn_s_barrier();
  __builtin_amdgcn_sched_barrier(0);
  COMPUTE(cb);
  cb = (cb == 2) ? 0 : cb + 1;
  asm volatile("s_waitcnt vmcnt(0)" ::: "memory");
  __builtin_amdgcn_s_barrier();
  __builtin_amdgcn_sched_barrier(0);
  COMPUTE(cb);

  #pragma unroll
  for (int m = 0; m < 4; ++m)
    #pragma unroll
    for (int n = 0; n < 4; ++n){
      int row0 = rt0 * 16 + (wr * 4 + m) * 16 + ((lane >> 4) * 4);
      int col  = (ct0 + wc * 4 + n) * 16 + (lane & 15);
      #pragma unroll
      for (int r = 0; r < 4; ++r){
        int rr = row0 + r;
        if (col < NTIMES) outf[(size_t)rr * NTIMES + col] = acc[m][n][r];
      }
    }
}

// ---------------- score GEMM: 30 * pred_n @ emb_n^T (row-major sources) -----------
__global__ __launch_bounds__(256, 3) void k_score_p(
    const unsigned short* __restrict__ predb, const unsigned short* __restrict__ Eb,
    const float* __restrict__ invn, float* __restrict__ out){
  __shared__ __align__(1024) short sAll[3 * 8192];   // 48 KB staging, reused as scratch
  const int Kt = KT_E;
  int tid = threadIdx.x;
  int lane = tid & 63, wid = tid >> 6;
  int wr = wid >> 1, wc = wid & 1;
  int kq = lane >> 4, r16 = lane & 15;
  int ct0 = blockIdx.x * 8;
  const unsigned short* pA0 = predb + (size_t)(2 * wid * 16 + r16) * 512 + kq * 8;
  const unsigned short* pA1 = predb + (size_t)((2 * wid + 1) * 16 + r16) * 512 + kq * 8;
  const unsigned short* pB0 = Eb + (size_t)((ct0 + 2 * wid) * 16 + r16) * 512 + kq * 8;
  const unsigned short* pB1 = Eb + (size_t)((ct0 + 2 * wid + 1) * 16 + r16) * 512 + kq * 8;
  int so = 2 * wid * 512;
  f4v acc[4][4] = {};

  auto STAGE = [&](int buf, int kt){
    short* b = &sAll[buf * 8192];
    gload16(pA0 + kt * 32, b + so);
    gload16(pA1 + kt * 32, b + so + 512);
    gload16(pB0 + kt * 32, b + 4096 + so);
    gload16(pB1 + kt * 32, b + 4096 + so + 512);
  };
  auto COMPUTE = [&](int buf){
    const short* base = &sAll[buf * 8192];
    s8v af[4], bfr[4];
    #pragma unroll
    for (int m = 0; m < 4; ++m) af[m] = *reinterpret_cast<const s8v*>(base + (wr * 4 + m) * 512 + lane * 8);
    #pragma unroll
    for (int n = 0; n < 4; ++n) bfr[n] = *reinterpret_cast<const s8v*>(base + 4096 + (wc * 4 + n) * 512 + lane * 8);
    #pragma unroll
    for (int m = 0; m < 4; ++m)
      #pragma unroll
      for (int n = 0; n < 4; ++n)
        acc[m][n] = __builtin_amdgcn_mfma_f32_16x16x32_bf16(af[m], bfr[n], acc[m][n], 0, 0, 0);
  };

  STAGE(0, 0);
  STAGE(1, 1);
  int cb = 0, sb = 2;
  for (int kt = 0; kt < Kt - 2; ++kt){
    STAGE(sb, kt + 2);
    asm volatile("s_waitcnt vmcnt(8)" ::: "memory");
    __builtin_amdgcn_s_barrier();
    __builtin_amdgcn_sched_barrier(0);
    COMPUTE(cb);
    __builtin_amdgcn_s_barrier();
    cb = (cb == 2) ? 0 : cb + 1;
    sb = (sb == 2) ? 0 : sb + 1;
  }
  asm volatile("s_waitcnt vmcnt(4)" ::: "memory");
  __builtin_amdgcn_s_barrier();
  __builtin_amdgcn_sched_barrier(0);
  COMPUTE(cb);
  cb = (cb == 2) ? 0 : cb + 1;
  asm volatile("s_waitcnt vmcnt(0)" ::: "memory");
  __builtin_amdgcn_s_barrier();
  __builtin_amdgcn_sched_barrier(0);
  COMPUTE(cb);

  // ---- epilogue: per-wave LDS transpose -> coalesced float4 row stores ----
  __syncthreads();                                   // staging LDS now reusable
  float* scratch = reinterpret_cast<float*>(sAll) + wid * 2176;   // 32 rows x 68
  int colg = ct0 * 16 + wc * 64 + r16 * 4;           // this lane's 4-col base
  bool c_ok = colg < V_TOT;                          // V_TOT % 4 == 0
  float4 inv4 = float4{0.f, 0.f, 0.f, 0.f};
  if (c_ok){
    inv4 = *reinterpret_cast<const float4*>(invn + colg);
    inv4.x *= 30.f; inv4.y *= 30.f; inv4.z *= 30.f; inv4.w *= 30.f;
  }
  #pragma unroll
  for (int p = 0; p < 2; ++p){
    #pragma unroll
    for (int mm = 0; mm < 2; ++mm){
      int m = p * 2 + mm;
      #pragma unroll
      for (int n = 0; n < 4; ++n)
        #pragma unroll
        for (int r = 0; r < 4; ++r)
          scratch[(mm * 16 + kq * 4 + r) * 68 + n * 16 + r16] = acc[m][n][r];
    }
    #pragma unroll
    for (int i = 0; i < 8; ++i){
      int row_r = i * 4 + kq;                        // 0..31
      float4 v = *reinterpret_cast<const float4*>(scratch + row_r * 68 + r16 * 4);
      if (c_ok){
        float4 o;
        o.x = v.x * inv4.x; o.y = v.y * inv4.y; o.z = v.z * inv4.z; o.w = v.w * inv4.w;
        int grr = wr * 64 + p * 32 + row_r;
        *reinterpret_cast<float4*>(out + (size_t)grr * V_TOT + colg) = o;
      }
    }
  }
}

// ---------------- 128x512 bf16 MFMA GEMM, row-major A [M][2560], Bt [512][2560] ----
// Depth-2 ring, 80 KB LDS -> 2 blocks/CU via LDS; launch_bounds(512,2) keeps
// VGPR cap at 128 so the 128-reg accumulator does NOT spill (round-15 lesson).
// MODE 1: h1 -> Az h-section (in-place, per-block rows only). MODE 2: h2 row-major.
template<int MODE>
__global__ __launch_bounds__(512, 2) void k_gemm512(
    const unsigned short* __restrict__ A, const unsigned short* __restrict__ Bt,
    const float* __restrict__ bias, unsigned short* __restrict__ outh,
    unsigned short* __restrict__ Az_h){
  __shared__ __align__(1024) short sAll[2 * 20480];  // 2 bufs x (A 8KB + B 32KB) = 80KB
  const int Kt = KT_L;
  int tid = threadIdx.x;
  int lane = tid & 63, wid = tid >> 6;               // 8 waves
  int wr = wid >> 2, wc = wid & 3;                   // 2x4 wave grid, wave-tile 64x128
  int r16 = lane & 15, kq = lane >> 4;
  int blk = blockIdx.x;                              // 236 blocks
  // A: wave stages rows blk*128 + wid*16 + r16, 16B chunk at k = kt*32 + kq*8
  const unsigned short* pA = A + (size_t)(blk * 128 + wid * 16 + r16) * KL + kq * 8;
  // B: wave stages col-tiles wid*4+c -> Bt rows (wid*4+c)*16 + r16
  const unsigned short* pB0 = Bt + (size_t)((wid * 4 + 0) * 16 + r16) * KL + kq * 8;
  const unsigned short* pB1 = Bt + (size_t)((wid * 4 + 1) * 16 + r16) * KL + kq * 8;
  const unsigned short* pB2 = Bt + (size_t)((wid * 4 + 2) * 16 + r16) * KL + kq * 8;
  const unsigned short* pB3 = Bt + (size_t)((wid * 4 + 3) * 16 + r16) * KL + kq * 8;
  int soA = wid * 512;
  int soB = 4096 + wid * 4 * 512;
  f4v acc[4][8] = {};

  auto STAGE = [&](int buf, int kt){
    short* b = &sAll[buf * 20480];
    gload16(pA  + kt * 32, b + soA);
    gload16(pB0 + kt * 32, b + soB);
    gload16(pB1 + kt * 32, b + soB +  512);
    gload16(pB2 + kt * 32, b + soB + 1024);
    gload16(pB3 + kt * 32, b + soB + 1536);
  };
  auto COMPUTE = [&](int buf){
    const short* base = &sAll[buf * 20480];
    s8v af[4], bfr[8];
    #pragma unroll
    for (int m = 0; m < 4; ++m) af[m] = *reinterpret_cast<const s8v*>(base + (wr * 4 + m) * 512 + lane * 8);
    #pragma unroll
    for (int n = 0; n < 8; ++n) bfr[n] = *reinterpret_cast<const s8v*>(base + 4096 + (wc * 8 + n) * 512 + lane * 8);
    __builtin_amdgcn_s_setprio(1);
    #pragma unroll
    for (int m = 0; m < 4; ++m)
      #pragma unroll
      for (int n = 0; n < 8; ++n)
        acc[m][n] = __builtin_amdgcn_mfma_f32_16x16x32_bf16(af[m], bfr[n], acc[m][n], 0, 0, 0);
    __builtin_amdgcn_s_setprio(0);
  };

  STAGE(0, 0);
  int cb = 0;
  for (int kt = 0; kt < Kt - 1; ++kt){
    STAGE(cb ^ 1, kt + 1);                 // 5 next-step loads issued
    asm volatile("s_waitcnt vmcnt(5)" ::: "memory");   // current step's 5 landed
    __builtin_amdgcn_s_barrier();
    __builtin_amdgcn_sched_barrier(0);
    COMPUTE(cb);
    __builtin_amdgcn_s_barrier();          // reads done before next STAGE overwrites
    cb ^= 1;
  }
  asm volatile("s_waitcnt vmcnt(0)" ::: "memory");
  __builtin_amdgcn_s_barrier();
  __builtin_amdgcn_sched_barrier(0);
  COMPUTE(cb);

  int R0 = blk * 128 + wr * 64 + ((lane >> 4) * 4);
  int C0 = wc * 128 + (lane & 15);
  #pragma unroll
  for (int m = 0; m < 4; ++m)
    #pragma unroll
    for (int r4 = 0; r4 < 4; ++r4){
      int rr = R0 + m * 16 + r4;
      if (rr < NN){
        #pragma unroll
        for (int n = 0; n < 8; ++n){
          int col = C0 + n * 16;
          float v = acc[m][n][r4] + bias[col];
          if constexpr (MODE == 1){
            v = fmaxf(v, 0.f);
            Az_h[(size_t)rr * KL + 2048 + col] = f2bf(v);   // in-place h-section
          } else {
            outh[(size_t)rr * 512 + col] = f2bf(v);
          }
        }
      }
    }
}

// ---------------- fused per-edge gate weight + dst bucketing ----------------
__global__ __launch_bounds__(256) void k_edgeprep(const int* __restrict__ ebatch,
    const int* __restrict__ st, const int* __restrict__ et,
    const float* __restrict__ enorm, const float* __restrict__ M2,
    const int* __restrict__ ei,
    float* __restrict__ we, int* __restrict__ cnt, int* __restrict__ lists){
  int e = blockIdx.x * 256 + threadIdx.x;
  if (e >= NEDGE) return;
  int b = ebatch[e];
  float s = 0.5f * (M2[(size_t)b * NTIMES + st[e]] + M2[(size_t)b * NTIMES + et[e]]);
  we[e] = (1.f / (1.f + expf(-s))) * enorm[e];
  int dst = ei[NEDGE + e];
  int slot = atomicAdd(&cnt[dst], 1);
  if (slot < 64) lists[(size_t)dst * 64 + slot] = e;
}

// ---------------- edge aggregation: z[n,b,:] += (w*att[t,b]) * x[src,:] -----------
// xsrc: row-major with row stride KL (Az h/x-section); z written row-major to Az.
__global__ __launch_bounds__(256) void k_edge_agg(const unsigned short* __restrict__ xsrc,
    const int* __restrict__ ei, const int* __restrict__ etype,
    const float* __restrict__ we, const float* __restrict__ att,
    const int* __restrict__ cnt, const int* __restrict__ lists,
    unsigned short* __restrict__ Az){
  __shared__ float satt[NREL * NBAS];
  __shared__ int sed[4][64];
  for (int i = threadIdx.x; i < NREL * NBAS; i += 256) satt[i] = att[i];
  int wid = threadIdx.x >> 6, lane = threadIdx.x & 63;
  int n = blockIdx.x * 4 + wid;
  int deg = min(cnt[n], 64);
  int eid = (lane < deg) ? lists[(size_t)n * 64 + lane] : 0x7fffffff;
  int rank = 0;
  for (int j = 0; j < 64; ++j){
    int v = __shfl(eid, j);
    rank += (v < eid) ? 1 : 0;
  }
  __syncthreads();
  if (lane < deg) sed[wid][rank] = eid;
  __syncthreads();
  float acc[NBAS][8] = {};
  if (deg > 0){
    int my_e = sed[wid][(lane < deg) ? lane : 0];
    int my_s = ei[my_e];
    int my_t = etype[my_e];
    float my_w = we[my_e];
    float c0l = my_w * satt[my_t * 4 + 0];
    float c1l = my_w * satt[my_t * 4 + 1];
    float c2l = my_w * satt[my_t * 4 + 2];
    float c3l = my_w * satt[my_t * 4 + 3];
    int s0 = __shfl(my_s, 0);
    s8v xv = *reinterpret_cast<const s8v*>(xsrc + (size_t)s0 * KL + lane * 8);
    for (int j = 0; j < deg; ++j){
      s8v xn = xv;
      if (j + 1 < deg){
        int sn = __shfl(my_s, j + 1);
        xn = *reinterpret_cast<const s8v*>(xsrc + (size_t)sn * KL + lane * 8);
      }
      float c0 = __shfl(c0l, j), c1 = __shfl(c1l, j);
      float c2 = __shfl(c2l, j), c3 = __shfl(c3l, j);
      #pragma unroll
      for (int jj = 0; jj < 8; ++jj){
        float x = bf2f((unsigned short)xv[jj]);
        acc[0][jj] = fmaf(c0, x, acc[0][jj]);
        acc[1][jj] = fmaf(c1, x, acc[1][jj]);
        acc[2][jj] = fmaf(c2, x, acc[2][jj]);
        acc[3][jj] = fmaf(c3, x, acc[3][jj]);
      }
      xv = xn;
    }
  }
  #pragma unroll
  for (int b = 0; b < NBAS; ++b){
    s8v o;
    #pragma unroll
    for (int jj = 0; jj < 8; ++jj) o[jj] = (short)f2bf(acc[b][jj]);
    *reinterpret_cast<s8v*>(Az + (size_t)n * KL + b * 512 + lane * 8) = o;
  }
}

// ---------------- pooling + pred assembly + normalize (row-major bf16 out) --------
__global__ __launch_bounds__(256) void k_pred(const unsigned short* __restrict__ h2,
    const float* __restrict__ emb, const int* __restrict__ uniq,
    const int* __restrict__ pent_idx, const int* __restrict__ ptime_idx,
    const int* __restrict__ ent_c, const int* __restrict__ time_c,
    const float* __restrict__ qlin, const float* __restrict__ pent,
    unsigned short* __restrict__ predb){
  __shared__ float sacc[4][512];
  int b = blockIdx.x;
  int wid = threadIdx.x >> 6, lane = threadIdx.x & 63;
  float a[8] = {};
  if (wid < 2){
    for (int j = wid * 32; j < wid * 32 + 32; ++j){
      int idx = pent_idx[b * PENT + j];
      if (idx < NN){
        s8v hv = *reinterpret_cast<const s8v*>(h2 + (size_t)idx * 512 + lane * 8);
        #pragma unroll
        for (int jj = 0; jj < 8; ++jj) a[jj] += bf2f((unsigned short)hv[jj]);
      }
    }
  } else {
    for (int j = (wid - 2) * 16; j < (wid - 2) * 16 + 16; ++j){
      int ti = ptime_idx[b * PTIME + j];
      if (ti < TUNIQ){
        const float* p = emb + (size_t)(NUM_ENT + uniq[ti]) * 512 + lane * 8;
        #pragma unroll
        for (int jj = 0; jj < 8; ++jj) a[jj] += p[jj];
      }
    }
  }
  #pragma unroll
  for (int jj = 0; jj < 8; ++jj) sacc[wid][lane * 8 + jj] = a[jj];
  __syncthreads();
  if (wid == 0){
    float ce = 1.f / (float)ent_c[b], ct = 1.f / (float)time_c[b];
    float p = pent[b];
    float pr[8]; float ss = 0.f;
    #pragma unroll
    for (int jj = 0; jj < 8; ++jj){
      int i = lane * 8 + jj;
      float ae = sacc[0][i] + sacc[1][i];
      float at = sacc[2][i] + sacc[3][i];
      float v = (qlin[(size_t)b * 512 + i] + ae * ce * p + at * ct * (1.f - p)) * (1.f / 3.f);
      pr[jj] = v; ss += v * v;
    }
    ss += __shfl_xor(ss, 32); ss += __shfl_xor(ss, 16); ss += __shfl_xor(ss, 8);
    ss += __shfl_xor(ss, 4);  ss += __shfl_xor(ss, 2);  ss += __shfl_xor(ss, 1);
    float inv = 1.f / fmaxf(sqrtf(ss), 1e-8f);
    s8v o;
    #pragma unroll
    for (int jj = 0; jj < 8; ++jj) o[jj] = (short)f2bf(pr[jj] * inv);
    *reinterpret_cast<s8v*>(predb + (size_t)b * 512 + lane * 8) = o;
  }
}

// ---------------- launch ----------------
extern "C" void kernel_launch(void* const* d_in, const int* in_sizes, int n_in,
                              void* d_out, int out_size, void* d_ws, size_t ws_size,
                              hipStream_t stream){
  const float* emb    = (const float*)d_in[0];
  const float* basis1 = (const float*)d_in[1];
  const float* att1   = (const float*)d_in[2];
  const float* root1  = (const float*)d_in[3];
  const float* bias1  = (const float*)d_in[4];
  const float* basis2 = (const float*)d_in[5];
  const float* att2   = (const float*)d_in[6];
  const float* root2  = (const float*)d_in[7];
  const float* bias2  = (const float*)d_in[8];
  const float* W_lin  = (const float*)d_in[9];
  const float* b_lin  = (const float*)d_in[10];
  const float* W_attn = (const float*)d_in[11];
  const float* b_attn = (const float*)d_in[12];
  const float* W_prob = (const float*)d_in[13];
  const float* b_prob = (const float*)d_in[14];
  const float* ques   = (const float*)d_in[15];
  const int* x_idx    = (const int*)d_in[16];
  const int* eidx     = (const int*)d_in[17];
  const int* etype    = (const int*)d_in[18];
  const int* stime    = (const int*)d_in[19];
  const int* etime    = (const int*)d_in[20];
  const int* ebatch   = (const int*)d_in[21];
  const float* enorm  = (const float*)d_in[22];
  const int* uniq     = (const int*)d_in[23];
  const int* pent_i   = (const int*)d_in[24];
  const int* ptime_i  = (const int*)d_in[25];
  const int* ent_c    = (const int*)d_in[26];
  const int* time_c   = (const int*)d_in[27];
  float* out = (float*)d_out;

  char* w = (char*)d_ws;
  size_t off = 0;
  auto alloc = [&](size_t bytes)->char*{ char* p = w + off; off += (bytes + 255) & ~(size_t)255; return p; };
  unsigned short* Eb   = (unsigned short*)alloc((size_t)V_PAD * 512 * 2);        // 112.9 MB
  float*          invn = (float*)alloc((size_t)V_PAD * 4);
  unsigned short* Az   = (unsigned short*)alloc((size_t)M_PAD2 * KL * 2);        // 154.7 MB
  unsigned short* Bt1  = (unsigned short*)alloc((size_t)512 * KL * 2);
  unsigned short* Bt2  = (unsigned short*)alloc((size_t)512 * KL * 2);
  unsigned short* h2   = (unsigned short*)alloc((size_t)NN * 512 * 2);           // 30.7 MB
  float* M2    = (float*)alloc((size_t)BATCH * NTIMES * 4);
  float* we    = (float*)alloc((size_t)NEDGE * 4);
  float* qlin  = (float*)alloc((size_t)BATCH * 512 * 4);
  float* pent  = (float*)alloc(1024);
  unsigned short* qat   = (unsigned short*)alloc((size_t)BATCH * 512 * 2);
  unsigned short* predb = (unsigned short*)alloc((size_t)BATCH * 512 * 2);
  int* cnt   = (int*)alloc((size_t)NN * 4);
  int* lists = (int*)alloc((size_t)NN * 64 * 4);
  (void)ws_size; (void)in_sizes; (void)n_in; (void)out_size;

  // 1. fused prep: Eb+invnorms | Bt packs | x gather into Az x-section
  k_prep<<<VCONV + PACKB_BLKS + GATH_BLKS, 256, 0, stream>>>(
      emb, basis1, root1, basis2, root2, x_idx,
      Eb, invn, Bt1, Bt2, Az);
  // 2. question projections
  k_small2<<<33, 256, 0, stream>>>(ques, W_lin, b_lin, W_attn, b_attn, W_prob, b_prob,
                                   qlin, qat, pent);
  // 3. M2 = q_attn @ time_emb^T
  k_gemm_m2<<<dim3(1, 79), 256, 0, stream>>>(qat, Eb, M2);
  // 4. fused edge gate + bucketing
  hipMemsetAsync(cnt, 0, (size_t)NN * 4, stream);
  k_edgeprep<<<(NEDGE + 255) / 256, 256, 0, stream>>>(ebatch, stime, etime, enorm, M2,
                                                      eidx, we, cnt, lists);
  // 5. layer 1: agg (x from Az x-section) -> gemm (h1 written in-place to x-section)
  k_edge_agg<<<NN / 4, 256, 0, stream>>>(Az + 2048, eidx, etype, we, att1, cnt, lists, Az);
  k_gemm512<1><<<236, 512, 0, stream>>>(Az, Bt1, bias1, nullptr, Az);
  // 6. layer 2: agg (h1 from same slot) -> gemm (h2 row-major)
  k_edge_agg<<<NN / 4, 256, 0, stream>>>(Az + 2048, eidx, etype, we, att2, cnt, lists, Az);
  k_gemm512<2><<<236, 512, 0, stream>>>(Az, Bt2, bias2, h2, nullptr);
  // 7. pooling + pred (row-major bf16)
  k_pred<<<BATCH, 256, 0, stream>>>(h2, emb, uniq, pent_i, ptime_i, ent_c, time_c,
                                    qlin, pent, predb);
  // 8. score = 30 * pred_n @ emb_n^T
  k_score_p<<<861, 256, 0, stream>>>(predb, Eb, invn, out);
}